// Round 2
// baseline (661.585 us; speedup 1.0000x reference)
//
#include <hip/hip_runtime.h>
#include <math.h>
#include <stdint.h>

#define NB 512
#define NT 20000
#define CAP 64
#define CHUNK 100
#define NC 200

static_assert(CHUNK * NC == NT, "chunking must cover all steps");

#define PI_F 3.14159265358979323846f

__device__ __forceinline__ float3 f3(float x, float y, float z) { return make_float3(x, y, z); }

__device__ __forceinline__ float3 norm3(float3 v) {
    float n = sqrtf(v.x * v.x + v.y * v.y + v.z * v.z);
    return f3(v.x / n, v.y / n, v.z / n);
}
__device__ __forceinline__ float3 cross3(float3 a, float3 b) {
    return f3(a.y * b.z - a.z * b.y, a.z * b.x - a.x * b.z, a.x * b.y - a.y * b.x);
}
__device__ __forceinline__ float dot3(float3 a, float3 b) { return a.x * b.x + a.y * b.y + a.z * b.z; }
__device__ __forceinline__ float3 orth3(float3 v, float3 u) {
    float d = dot3(v, u) / dot3(u, u);
    return f3(v.x - d * u.x, v.y - d * u.y, v.z - d * u.z);
}
// R v = c v + s (u x v) + (1-c)(u.v) u   (Rodrigues applied directly)
__device__ __forceinline__ float3 rotv(float3 u, float c, float s, float3 v) {
    float3 cv = cross3(u, v);
    float du = dot3(u, v) * (1.0f - c);
    return f3(c * v.x + s * cv.x + du * u.x,
              c * v.y + s * cv.y + du * u.y,
              c * v.z + s * cv.z + du * u.z);
}

__device__ __forceinline__ float cauchy_ang(float u, float sigma) {
    float x = PI_F * (u - 0.5f);          // f32 argument, as in reference
    float t = (float)tan((double)x);      // near-correctly-rounded tan of that f32 arg
    float a = sigma * t;                  // mu = 0
    if (!isfinite(a)) a = 0.0f;
    return fmodf(a, PI_F);
}

// ---- kernel 1: initial frame + 64 tumble rotations -> e0s[b][65][3] ----
__global__ void k_frames(const float* __restrict__ v0, const float* __restrict__ v1,
                         const float* __restrict__ up, const float* __restrict__ un,
                         float* __restrict__ e0s) {
    int b = blockIdx.x * blockDim.x + threadIdx.x;
    if (b >= NB) return;
    float3 a0 = f3(v0[b * 3], v0[b * 3 + 1], v0[b * 3 + 2]);
    float3 a1 = f3(v1[b * 3], v1[b * 3 + 1], v1[b * 3 + 2]);
    float3 e0 = norm3(a0);
    float3 e1 = norm3(orth3(a1, e0));
    float3 e2 = norm3(cross3(e0, e1));
    float* o = e0s + (size_t)b * (CAP + 1) * 3;
    o[0] = e0.x; o[1] = e0.y; o[2] = e0.z;
    for (int k = 0; k < CAP; k++) {
        float ap = cauchy_ang(up[b * CAP + k], 0.1f);
        float an = cauchy_ang(un[b * CAP + k], 0.5f);
        // planar rotation about e2
        float cp = cosf(ap), sp = sinf(ap);
        float3 e0r = rotv(e2, cp, sp, e0);
        float3 e1r = rotv(e2, cp, sp, e1);
        e0 = norm3(e0r);
        e1 = norm3(e1r);
        e1 = norm3(orth3(e1, e0));
        e2 = norm3(cross3(e0, e1));
        // nonplanar rotation about e1
        float cn = cosf(an), sn = sinf(an);
        e0 = norm3(rotv(e1, cn, sn, e0));
        e1 = norm3(orth3(e1, e0));
        e2 = norm3(cross3(e0, e1));
        o[(k + 1) * 3] = e0.x; o[(k + 1) * 3 + 1] = e0.y; o[(k + 1) * 3 + 2] = e0.z;
    }
}

// ---- kernel 2: per-chunk composed state map + per-entry-state tumble counts ----
__global__ __launch_bounds__(256) void k_chunk_summary(const float* __restrict__ r0,
                                                       const float* __restrict__ r1,
                                                       uint32_t* __restrict__ mapP,
                                                       uint32_t* __restrict__ cntP) {
    int b = blockIdx.x, c = threadIdx.x;
    if (c >= NC) return;
    const float4* p0 = (const float4*)(r0 + (size_t)b * NT + c * CHUNK);
    const float4* p1 = (const float4*)(r1 + (size_t)b * NT + c * CHUNK);
    int s0 = 0, s1 = 1, s2 = 2;
    int c0 = 0, c1 = 0, c2 = 0;
    bool first_chunk = (c == 0);
    for (int i = 0; i < CHUNK / 4; i++) {
        float4 a = p0[i], d = p1[i];
        float ra[4] = {a.x, a.y, a.z, a.w};
        float rd[4] = {d.x, d.y, d.z, d.w};
#pragma unroll
        for (int j = 0; j < 4; j++) {
            int f0 = (ra[j] < 1e-3f) ? 1 : ((ra[j] > (1.0f - 1e-3f)) ? 2 : 0);
            int f1 = (rd[j] < 1e-3f) ? 0 : 1;   // from1 == from2 in the reference
            s0 = (s0 == 0) ? f0 : f1;
            s1 = (s1 == 0) ? f0 : f1;
            s2 = (s2 == 0) ? f0 : f1;
            bool skip = first_chunk && (i == 0) && (j == 0);  // tumble[t=0] forced False
            c0 += (s0 == 2 && !skip);
            c1 += (s1 == 2 && !skip);
            c2 += (s2 == 2 && !skip);
        }
    }
    mapP[b * NC + c] = (uint32_t)(s0 | (s1 << 2) | (s2 << 4));
    cntP[b * NC + c] = (uint32_t)(c0 | (c1 << 8) | (c2 << 16));
}

// ---- kernel 3: per-b scan over chunks -> entry state + entry tumble count ----
__global__ void k_scan_state(const uint32_t* __restrict__ mapP, const uint32_t* __restrict__ cntP,
                             uint32_t* __restrict__ entry) {
    int b = blockIdx.x * blockDim.x + threadIdx.x;
    if (b >= NB) return;
    uint32_t s = 0, C = 0;
    for (int c = 0; c < NC; c++) {
        uint32_t m = mapP[b * NC + c];
        uint32_t k = cntP[b * NC + c];
        entry[b * NC + c] = s | (C << 2);
        C += (k >> (8 * s)) & 0xFF;
        s = (m >> (2 * s)) & 3;
    }
}

// ---- kernels 4 & 6: walk a chunk from known entry state/count.
//      MODE 0: accumulate chunk velocity sum.  MODE 1: write positions. ----
template <int MODE>
__global__ __launch_bounds__(256) void k_walk(const float* __restrict__ r0, const float* __restrict__ r1,
                                              const float* __restrict__ x0, const float* __restrict__ e0s,
                                              const uint32_t* __restrict__ entry,
                                              const float* __restrict__ epos,
                                              float* __restrict__ cvel, float* __restrict__ out) {
    __shared__ float se[(CAP + 1) * 3];
    int b = blockIdx.x, c = threadIdx.x;
    for (int i = threadIdx.x; i < (CAP + 1) * 3; i += blockDim.x)
        se[i] = e0s[(size_t)b * (CAP + 1) * 3 + i];
    __syncthreads();
    if (c >= NC) return;
    uint32_t e = entry[b * NC + c];
    int s = (int)(e & 3);
    int C = (int)(e >> 2);
    float px = 0.f, py = 0.f, pz = 0.f;
    if (MODE == 1) {
        const float* pp = epos + (size_t)(b * NC + c) * 3;
        px = pp[0]; py = pp[1]; pz = pp[2];
    }
    const float4* p0 = (const float4*)(r0 + (size_t)b * NT + c * CHUNK);
    const float4* p1 = (const float4*)(r1 + (size_t)b * NT + c * CHUNK);
    float* op = out + (size_t)(b * NT + c * CHUNK) * 3;
    int gt0 = c * CHUNK;
    for (int i = 0; i < CHUNK / 4; i++) {
        float4 a = p0[i], d = p1[i];
        float ra[4] = {a.x, a.y, a.z, a.w};
        float rd[4] = {d.x, d.y, d.z, d.w};
#pragma unroll
        for (int j = 0; j < 4; j++) {
            int f0 = (ra[j] < 1e-3f) ? 1 : ((ra[j] > (1.0f - 1e-3f)) ? 2 : 0);
            int f1 = (rd[j] < 1e-3f) ? 0 : 1;
            s = (s == 0) ? f0 : f1;
            int gt = gt0 + i * 4 + j;
            float vx, vy, vz;
            if (gt == 0) {
                vx = x0[b * 3]; vy = x0[b * 3 + 1]; vz = x0[b * 3 + 2];  // vel[:,0,:]=x0, no count
            } else if (s == 2) {
                C++;  // tumble: vel = 0
                vx = 0.f; vy = 0.f; vz = 0.f;
            } else {
                int idx = C - 1;
                idx = idx < 0 ? 0 : (idx > CAP ? CAP : idx);
                float spd = (s == 1) ? 5e-3f : 1e-3f;
                vx = se[idx * 3] * spd; vy = se[idx * 3 + 1] * spd; vz = se[idx * 3 + 2] * spd;
            }
            px += vx; py += vy; pz += vz;
            if (MODE == 1) {
                int o = (i * 4 + j) * 3;
                op[o] = px; op[o + 1] = py; op[o + 2] = pz;
            }
        }
    }
    if (MODE == 0) {
        float* cv = cvel + (size_t)(b * NC + c) * 3;
        cv[0] = px; cv[1] = py; cv[2] = pz;
    }
}

// ---- kernel 5: per-b scan of chunk velocity sums -> entry positions ----
__global__ void k_scan_pos(const float* __restrict__ cvel, float* __restrict__ epos) {
    int b = blockIdx.x * blockDim.x + threadIdx.x;
    if (b >= NB) return;
    float px = 0.f, py = 0.f, pz = 0.f;
    for (int c = 0; c < NC; c++) {
        float* ep = epos + (size_t)(b * NC + c) * 3;
        ep[0] = px; ep[1] = py; ep[2] = pz;
        const float* cv = cvel + (size_t)(b * NC + c) * 3;
        px += cv[0]; py += cv[1]; pz += cv[2];
    }
}

extern "C" void kernel_launch(void* const* d_in, const int* in_sizes, int n_in,
                              void* d_out, int out_size, void* d_ws, size_t ws_size,
                              hipStream_t stream) {
    const float* x0 = (const float*)d_in[0];
    const float* v0 = (const float*)d_in[1];
    const float* v1 = (const float*)d_in[2];
    const float* r0 = (const float*)d_in[3];
    const float* r1 = (const float*)d_in[4];
    const float* up = (const float*)d_in[5];
    const float* un = (const float*)d_in[6];
    float* out = (float*)d_out;

    char* w = (char*)d_ws;
    float* e0s = (float*)w;      w += (size_t)NB * (CAP + 1) * 3 * sizeof(float);
    uint32_t* mapP = (uint32_t*)w; w += (size_t)NB * NC * 4;
    uint32_t* cntP = (uint32_t*)w; w += (size_t)NB * NC * 4;
    uint32_t* entry = (uint32_t*)w; w += (size_t)NB * NC * 4;
    float* cvel = (float*)w;     w += (size_t)NB * NC * 3 * sizeof(float);
    float* epos = (float*)w;     w += (size_t)NB * NC * 3 * sizeof(float);

    k_frames<<<dim3((NB + 255) / 256), dim3(256), 0, stream>>>(v0, v1, up, un, e0s);
    k_chunk_summary<<<dim3(NB), dim3(256), 0, stream>>>(r0, r1, mapP, cntP);
    k_scan_state<<<dim3((NB + 255) / 256), dim3(256), 0, stream>>>(mapP, cntP, entry);
    k_walk<0><<<dim3(NB), dim3(256), 0, stream>>>(r0, r1, x0, e0s, entry, nullptr, cvel, nullptr);
    k_scan_pos<<<dim3((NB + 255) / 256), dim3(256), 0, stream>>>(cvel, epos);
    k_walk<1><<<dim3(NB), dim3(256), 0, stream>>>(r0, r1, x0, e0s, entry, epos, nullptr, out);
}

// Round 3
// 401.451 us; speedup vs baseline: 1.6480x; 1.6480x over previous
//
#include <hip/hip_runtime.h>
#include <math.h>
#include <stdint.h>

#define NB 512
#define NT 20000
#define CAP 64
#define CHUNK 100
#define NC 200
#define NWORDS ((NB * NT) / 32)   // 320000 u32 per bit-plane

static_assert(CHUNK * NC == NT, "chunking must cover all steps");
static_assert((NB * NT) % 64 == 0, "pack wave alignment");
static_assert(NT % 32 == 0, "b*NT word-aligned");

#define PI_F 3.14159265358979323846f

__device__ __forceinline__ float3 f3(float x, float y, float z) { return make_float3(x, y, z); }

__device__ __forceinline__ float3 norm3(float3 v) {
    float n = sqrtf(v.x * v.x + v.y * v.y + v.z * v.z);
    return f3(v.x / n, v.y / n, v.z / n);
}
__device__ __forceinline__ float3 cross3(float3 a, float3 b) {
    return f3(a.y * b.z - a.z * b.y, a.z * b.x - a.x * b.z, a.x * b.y - a.y * b.x);
}
__device__ __forceinline__ float dot3(float3 a, float3 b) { return a.x * b.x + a.y * b.y + a.z * b.z; }
__device__ __forceinline__ float3 orth3(float3 v, float3 u) {
    float d = dot3(v, u) / dot3(u, u);
    return f3(v.x - d * u.x, v.y - d * u.y, v.z - d * u.z);
}
// R v = c v + s (u x v) + (1-c)(u.v) u
__device__ __forceinline__ float3 rotv(float3 u, float c, float s, float3 v) {
    float3 cv = cross3(u, v);
    float du = dot3(u, v) * (1.0f - c);
    return f3(c * v.x + s * cv.x + du * u.x,
              c * v.y + s * cv.y + du * u.y,
              c * v.z + s * cv.z + du * u.z);
}

__device__ __forceinline__ float cauchy_ang(float u, float sigma) {
    float x = PI_F * (u - 0.5f);          // f32 argument, as in reference
    float t = (float)tan((double)x);      // near-correctly-rounded tan of that f32 arg
    float a = sigma * t;                  // mu = 0
    if (!isfinite(a)) a = 0.0f;
    return fmodf(a, PI_F);
}

// ---- kernel 1: parallel Cauchy angles + trig -> trig[k][b] = {cp,sp,cn,sn} ----
__global__ __launch_bounds__(256) void k_angles(const float* __restrict__ up, const float* __restrict__ un,
                                                float* __restrict__ trig) {
    int tid = blockIdx.x * 256 + threadIdx.x;   // tid = k*NB + b
    int k = tid >> 9, b = tid & (NB - 1);
    float ap = cauchy_ang(up[b * CAP + k], 0.1f);
    float an = cauchy_ang(un[b * CAP + k], 0.5f);
    ((float4*)trig)[tid] = make_float4(cosf(ap), sinf(ap), cosf(an), sinf(an));
}

// ---- kernel 2: sequential frame chain (pure f32 arith) -> e0s[b][65][3] ----
__global__ __launch_bounds__(64) void k_chain(const float* __restrict__ v0, const float* __restrict__ v1,
                                              const float* __restrict__ trig, float* __restrict__ e0s) {
    int b = blockIdx.x * 64 + threadIdx.x;
    if (b >= NB) return;
    float3 a0 = f3(v0[b * 3], v0[b * 3 + 1], v0[b * 3 + 2]);
    float3 a1 = f3(v1[b * 3], v1[b * 3 + 1], v1[b * 3 + 2]);
    float3 e0 = norm3(a0);
    float3 e1 = norm3(orth3(a1, e0));
    float3 e2 = norm3(cross3(e0, e1));
    float* o = e0s + (size_t)b * (CAP + 1) * 3;
    o[0] = e0.x; o[1] = e0.y; o[2] = e0.z;
    for (int k = 0; k < CAP; k++) {
        float4 t4 = ((const float4*)trig)[k * NB + b];
        float cp = t4.x, sp = t4.y, cn = t4.z, sn = t4.w;
        float3 e0r = rotv(e2, cp, sp, e0);
        float3 e1r = rotv(e2, cp, sp, e1);
        e0 = norm3(e0r);
        e1 = norm3(e1r);
        e1 = norm3(orth3(e1, e0));
        e2 = norm3(cross3(e0, e1));
        e0 = norm3(rotv(e1, cn, sn, e0));
        e1 = norm3(orth3(e1, e0));
        e2 = norm3(cross3(e0, e1));
        o[(k + 1) * 3] = e0.x; o[(k + 1) * 3 + 1] = e0.y; o[(k + 1) * 3 + 2] = e0.z;
    }
}

// ---- kernel 3: one coalesced pass over r0/r1 -> 3 bit-planes (f0 lo/hi, f1) ----
__global__ __launch_bounds__(256) void k_pack(const float* __restrict__ r0, const float* __restrict__ r1,
                                              uint32_t* __restrict__ p0, uint32_t* __restrict__ p1,
                                              uint32_t* __restrict__ pf) {
    int g = blockIdx.x * 256 + threadIdx.x;     // flat step index b*NT + t
    float a = r0[g], d = r1[g];
    int f0 = (a < 1e-3f) ? 1 : ((a > (1.0f - 1e-3f)) ? 2 : 0);
    int f1 = (d < 1e-3f) ? 0 : 1;
    uint64_t b0 = __ballot(f0 & 1);
    uint64_t b1 = __ballot((f0 >> 1) & 1);
    uint64_t bf = __ballot(f1);
    if ((threadIdx.x & 63) == 0) {
        int w = g >> 6;
        ((uint64_t*)p0)[w] = b0;
        ((uint64_t*)p1)[w] = b1;
        ((uint64_t*)pf)[w] = bf;
    }
}

// align 100 bits starting at (w0*32 + off) into r[0..3], bit t of window = r[t>>5] bit (t&31)
__device__ __forceinline__ void load100(const uint32_t* __restrict__ p, int w0, int off, uint32_t r[4]) {
    uint32_t q0 = p[w0], q1 = p[w0 + 1], q2 = p[w0 + 2], q3 = p[w0 + 3], q4 = p[w0 + 4];
    r[0] = __builtin_amdgcn_alignbit(q1, q0, off);
    r[1] = __builtin_amdgcn_alignbit(q2, q1, off);
    r[2] = __builtin_amdgcn_alignbit(q3, q2, off);
    r[3] = __builtin_amdgcn_alignbit(q4, q3, off);
}

#define GETB(R, t) ((R[(t) >> 5] >> ((t) & 31)) & 1u)

// ---- kernel 4: per-chunk composed state map + per-entry-state tumble counts ----
__global__ __launch_bounds__(512) void k_summary(const uint32_t* __restrict__ p0, const uint32_t* __restrict__ p1,
                                                 const uint32_t* __restrict__ pf, uint32_t* __restrict__ comb) {
    int c = blockIdx.x, b = threadIdx.x;
    int g0 = b * NT + c * CHUNK;
    uint32_t R0[4], R1[4], RF[4];
    load100(p0, g0 >> 5, g0 & 31, R0);
    load100(p1, g0 >> 5, g0 & 31, R1);
    load100(pf, g0 >> 5, g0 & 31, RF);
    int s0 = 0, s1 = 1, s2 = 2, c0 = 0, c1 = 0, c2 = 0;
#pragma unroll
    for (int t = 0; t < CHUNK; t++) {
        int f0 = (int)(GETB(R0, t) | (GETB(R1, t) << 1));
        int f1 = (int)GETB(RF, t);
        s0 = (s0 == 0) ? f0 : f1;
        s1 = (s1 == 0) ? f0 : f1;
        s2 = (s2 == 0) ? f0 : f1;
        bool skip = (c == 0) && (t == 0);   // tumble[t=0] forced False
        c0 += (s0 == 2 && !skip);
        c1 += (s1 == 2 && !skip);
        c2 += (s2 == 2 && !skip);
    }
    comb[c * NB + b] = (uint32_t)(s0 | (s1 << 2) | (s2 << 4) | (c0 << 8) | (c1 << 16) | (c2 << 24));
}

// ---- kernel 5: per-b scan over chunks -> entry state + entry tumble count ----
__global__ void k_scan_state(const uint32_t* __restrict__ comb, uint32_t* __restrict__ entry) {
    int b = blockIdx.x * blockDim.x + threadIdx.x;
    if (b >= NB) return;
    uint32_t s = 0, C = 0;
#pragma unroll 4
    for (int c = 0; c < NC; c++) {
        uint32_t m = comb[c * NB + b];
        entry[c * NB + b] = s | (C << 2);
        C += (m >> (8 + 8 * s)) & 0xFF;
        s = (m >> (2 * s)) & 3;
    }
}

// ---- kernels 6 & 8: walk a chunk from bit-planes. MODE0: chunk vel sum. MODE1: write X ----
template <int MODE>
__global__ __launch_bounds__(256) void k_walk(const uint32_t* __restrict__ p0, const uint32_t* __restrict__ p1,
                                              const uint32_t* __restrict__ pf,
                                              const float* __restrict__ x0, const float* __restrict__ e0s,
                                              const uint32_t* __restrict__ entry,
                                              const float* __restrict__ epos,
                                              float* __restrict__ cvel, float* __restrict__ out) {
    __shared__ float se[(CAP + 1) * 3];
    int b = blockIdx.x, c = threadIdx.x;
    for (int i = threadIdx.x; i < (CAP + 1) * 3; i += blockDim.x)
        se[i] = e0s[(size_t)b * (CAP + 1) * 3 + i];
    __syncthreads();
    if (c >= NC) return;
    int g0 = b * NT + c * CHUNK;
    uint32_t R0[4], R1[4], RF[4];
    load100(p0, g0 >> 5, g0 & 31, R0);
    load100(p1, g0 >> 5, g0 & 31, R1);
    load100(pf, g0 >> 5, g0 & 31, RF);
    uint32_t e = entry[c * NB + b];
    int s = (int)(e & 3);
    int C = (int)(e >> 2);
    float px = 0.f, py = 0.f, pz = 0.f;
    if (MODE == 1) {
        const float* pp = epos + (size_t)(c * NB + b) * 3;
        px = pp[0]; py = pp[1]; pz = pp[2];
    }
    float* op = out + (size_t)(b * NT + c * CHUNK) * 3;
#pragma unroll
    for (int t = 0; t < CHUNK; t++) {
        int f0 = (int)(GETB(R0, t) | (GETB(R1, t) << 1));
        int f1 = (int)GETB(RF, t);
        s = (s == 0) ? f0 : f1;
        float vx, vy, vz;
        if (c == 0 && t == 0) {
            vx = x0[b * 3]; vy = x0[b * 3 + 1]; vz = x0[b * 3 + 2];   // vel[:,0,:]=x0, no count
        } else if (s == 2) {
            C++;  // tumble: vel = 0
            vx = 0.f; vy = 0.f; vz = 0.f;
        } else {
            int idx = C - 1;
            idx = idx < 0 ? 0 : (idx > CAP ? CAP : idx);
            float spd = (s == 1) ? 5e-3f : 1e-3f;
            vx = se[idx * 3] * spd; vy = se[idx * 3 + 1] * spd; vz = se[idx * 3 + 2] * spd;
        }
        px += vx; py += vy; pz += vz;
        if (MODE == 1) {
            op[t * 3] = px; op[t * 3 + 1] = py; op[t * 3 + 2] = pz;
        }
    }
    if (MODE == 0) {
        float* cv = cvel + (size_t)(c * NB + b) * 3;
        cv[0] = px; cv[1] = py; cv[2] = pz;
    }
}

// ---- kernel 7: per-b scan of chunk velocity sums -> entry positions ----
__global__ void k_scan_pos(const float* __restrict__ cvel, float* __restrict__ epos) {
    int b = blockIdx.x * blockDim.x + threadIdx.x;
    if (b >= NB) return;
    float px = 0.f, py = 0.f, pz = 0.f;
#pragma unroll 4
    for (int c = 0; c < NC; c++) {
        float* ep = epos + (size_t)(c * NB + b) * 3;
        ep[0] = px; ep[1] = py; ep[2] = pz;
        const float* cv = cvel + (size_t)(c * NB + b) * 3;
        px += cv[0]; py += cv[1]; pz += cv[2];
    }
}

extern "C" void kernel_launch(void* const* d_in, const int* in_sizes, int n_in,
                              void* d_out, int out_size, void* d_ws, size_t ws_size,
                              hipStream_t stream) {
    const float* x0 = (const float*)d_in[0];
    const float* v0 = (const float*)d_in[1];
    const float* v1 = (const float*)d_in[2];
    const float* r0 = (const float*)d_in[3];
    const float* r1 = (const float*)d_in[4];
    const float* up = (const float*)d_in[5];
    const float* un = (const float*)d_in[6];
    float* out = (float*)d_out;

    char* w = (char*)d_ws;
    float* trig = (float*)w;       w += (size_t)NB * CAP * 4 * sizeof(float);       // 512 kB
    float* e0s = (float*)w;        w += (size_t)NB * (CAP + 1) * 3 * sizeof(float); // 400 kB
    uint32_t* p0 = (uint32_t*)w;   w += (size_t)(NWORDS + 16) * 4;                  // 1.28 MB
    uint32_t* p1 = (uint32_t*)w;   w += (size_t)(NWORDS + 16) * 4;
    uint32_t* pf = (uint32_t*)w;   w += (size_t)(NWORDS + 16) * 4;
    uint32_t* comb = (uint32_t*)w; w += (size_t)NC * NB * 4;                        // 410 kB
    uint32_t* entry = (uint32_t*)w; w += (size_t)NC * NB * 4;
    float* cvel = (float*)w;       w += (size_t)NC * NB * 3 * sizeof(float);        // 1.23 MB
    float* epos = (float*)w;       w += (size_t)NC * NB * 3 * sizeof(float);

    k_angles<<<dim3(NB * CAP / 256), dim3(256), 0, stream>>>(up, un, trig);
    k_chain<<<dim3(NB / 64), dim3(64), 0, stream>>>(v0, v1, trig, e0s);
    k_pack<<<dim3(NB * NT / 256), dim3(256), 0, stream>>>(r0, r1, p0, p1, pf);
    k_summary<<<dim3(NC), dim3(NB), 0, stream>>>(p0, p1, pf, comb);
    k_scan_state<<<dim3(2), dim3(256), 0, stream>>>(comb, entry);
    k_walk<0><<<dim3(NB), dim3(256), 0, stream>>>(p0, p1, pf, x0, e0s, entry, nullptr, cvel, nullptr);
    k_scan_pos<<<dim3(2), dim3(256), 0, stream>>>(cvel, epos);
    k_walk<1><<<dim3(NB), dim3(256), 0, stream>>>(p0, p1, pf, x0, e0s, entry, epos, nullptr, out);
}

// Round 6
// 352.645 us; speedup vs baseline: 1.8761x; 1.1384x over previous
//
#include <hip/hip_runtime.h>
#include <math.h>
#include <stdint.h>

#define NB 512
#define NT 20000
#define CAP 64
#define CHUNK 80
#define NC 250          // NT / CHUNK
#define CPAD 21         // u32 words per chunk in LDS (20 data + 1 pad, gcd(21,32)=1)

static_assert(CHUNK * NC == NT, "chunking must cover all steps");
static_assert(CHUNK % 4 == 0, "byte-packing needs 4 | CHUNK");

#define PI_F 3.14159265358979323846f

__device__ __forceinline__ float3 f3(float x, float y, float z) { return make_float3(x, y, z); }

__device__ __forceinline__ float3 norm3(float3 v) {
    float n = sqrtf(v.x * v.x + v.y * v.y + v.z * v.z);
    return f3(v.x / n, v.y / n, v.z / n);
}
__device__ __forceinline__ float3 cross3(float3 a, float3 b) {
    return f3(a.y * b.z - a.z * b.y, a.z * b.x - a.x * b.z, a.x * b.y - a.y * b.x);
}
__device__ __forceinline__ float dot3(float3 a, float3 b) { return a.x * b.x + a.y * b.y + a.z * b.z; }
__device__ __forceinline__ float3 orth3(float3 v, float3 u) {
    float d = dot3(v, u) / dot3(u, u);
    return f3(v.x - d * u.x, v.y - d * u.y, v.z - d * u.z);
}
__device__ __forceinline__ float3 rotv(float3 u, float c, float s, float3 v) {
    float3 cv = cross3(u, v);
    float du = dot3(u, v) * (1.0f - c);
    return f3(c * v.x + s * cv.x + du * u.x,
              c * v.y + s * cv.y + du * u.y,
              c * v.z + s * cv.z + du * u.z);
}

__device__ __forceinline__ float cauchy_ang(float u, float sigma) {
    float x = PI_F * (u - 0.5f);          // f32 argument, as in reference
    float t = (float)tan((double)x);      // near-correctly-rounded tan of that f32 arg
    float a = sigma * t;                  // mu = 0
    if (!isfinite(a)) a = 0.0f;
    return fmodf(a, PI_F);
}

// ---- kernel 1: parallel Cauchy angles + trig -> trig[k][b] = {cp,sp,cn,sn} ----
__global__ __launch_bounds__(256) void k_angles(const float* __restrict__ up, const float* __restrict__ un,
                                                float* __restrict__ trig) {
    int tid = blockIdx.x * 256 + threadIdx.x;   // tid = k*NB + b
    int k = tid >> 9, b = tid & (NB - 1);
    float ap = cauchy_ang(up[b * CAP + k], 0.1f);
    float an = cauchy_ang(un[b * CAP + k], 0.5f);
    ((float4*)trig)[tid] = make_float4(cosf(ap), sinf(ap), cosf(an), sinf(an));
}

// ---- kernel 2: sequential frame chain (pure f32 arith) -> e0s[b][65][3] ----
__global__ __launch_bounds__(64) void k_chain(const float* __restrict__ v0, const float* __restrict__ v1,
                                              const float* __restrict__ trig, float* __restrict__ e0s) {
    int b = blockIdx.x * 64 + threadIdx.x;
    if (b >= NB) return;
    float3 a0 = f3(v0[b * 3], v0[b * 3 + 1], v0[b * 3 + 2]);
    float3 a1 = f3(v1[b * 3], v1[b * 3 + 1], v1[b * 3 + 2]);
    float3 e0 = norm3(a0);
    float3 e1 = norm3(orth3(a1, e0));
    float3 e2 = norm3(cross3(e0, e1));
    float* o = e0s + (size_t)b * (CAP + 1) * 3;
    o[0] = e0.x; o[1] = e0.y; o[2] = e0.z;
    for (int k = 0; k < CAP; k++) {
        float4 t4 = ((const float4*)trig)[k * NB + b];
        float cp = t4.x, sp = t4.y, cn = t4.z, sn = t4.w;
        float3 e0r = rotv(e2, cp, sp, e0);
        float3 e1r = rotv(e2, cp, sp, e1);
        e0 = norm3(e0r);
        e1 = norm3(e1r);
        e1 = norm3(orth3(e1, e0));
        e2 = norm3(cross3(e0, e1));
        e0 = norm3(rotv(e1, cn, sn, e0));
        e1 = norm3(orth3(e1, e0));
        e2 = norm3(cross3(e0, e1));
        o[(k + 1) * 3] = e0.x; o[(k + 1) * 3 + 1] = e0.y; o[(k + 1) * 3 + 2] = e0.z;
    }
}

// combine two scan elements: apply A then B.  elem = {map(3x2b), c0, c1, c2}
__device__ __forceinline__ uint4 comb2(uint4 A, uint4 B) {
    uint4 R;
    R.x = 0;
    // s = 0
    {
        unsigned ms = A.x & 3u;
        unsigned mf = (B.x >> (2u * ms)) & 3u;
        R.x |= mf;
        unsigned cB = (ms == 0u) ? B.y : ((ms == 1u) ? B.z : B.w);
        R.y = A.y + cB;
    }
    // s = 1
    {
        unsigned ms = (A.x >> 2) & 3u;
        unsigned mf = (B.x >> (2u * ms)) & 3u;
        R.x |= mf << 2;
        unsigned cB = (ms == 0u) ? B.y : ((ms == 1u) ? B.z : B.w);
        R.z = A.z + cB;
    }
    // s = 2
    {
        unsigned ms = (A.x >> 4) & 3u;
        unsigned mf = (B.x >> (2u * ms)) & 3u;
        R.x |= mf << 4;
        unsigned cB = (ms == 0u) ? B.y : ((ms == 1u) ? B.z : B.w);
        R.w = A.w + cB;
    }
    return R;
}

#define DECODE(dw, t, f0, f1)                                        \
    {                                                                \
        uint32_t by_ = (dw[(t) >> 2] >> (((t) & 3) * 8)) & 0xFFu;    \
        f0 = (int)(by_ & 3u);                                        \
        f1 = (int)((by_ >> 2) & 1u);                                 \
    }

// ---- kernel 3: the whole per-b pipeline in one block ----
__global__ __launch_bounds__(256) void k_row(const float* __restrict__ r0, const float* __restrict__ r1,
                                             const float* __restrict__ x0, const float* __restrict__ e0s,
                                             float* __restrict__ out) {
    __shared__ uint32_t dec[NC * CPAD];      // decision bytes, padded per chunk
    __shared__ float se[(CAP + 1) * 3];      // frame table
    __shared__ uint4 S[NC];                  // (map,counts) scan
    __shared__ float Px[NC], Py[NC], Pz[NC]; // position scan

    int b = blockIdx.x, tid = threadIdx.x;

    // ---- A: load frames + pack decision bytes into LDS ----
    for (int i = tid; i < (CAP + 1) * 3; i += 256)
        se[i] = e0s[(size_t)b * (CAP + 1) * 3 + i];

    const float4* q0 = (const float4*)(r0 + (size_t)b * NT);
    const float4* q1 = (const float4*)(r1 + (size_t)b * NT);
    for (int T = tid; T < NT / 4; T += 256) {
        float4 a = q0[T], d = q1[T];
        float ra[4] = {a.x, a.y, a.z, a.w};
        float rd[4] = {d.x, d.y, d.z, d.w};
        uint32_t w = 0;
#pragma unroll
        for (int j = 0; j < 4; j++) {
            int f0 = (ra[j] < 1e-3f) ? 1 : ((ra[j] > (1.0f - 1e-3f)) ? 2 : 0);
            int f1 = (rd[j] < 1e-3f) ? 0 : 1;
            w |= (uint32_t)(f0 | (f1 << 2)) << (8 * j);
        }
        int t0 = T * 4;
        int c = t0 / CHUNK;
        int o = t0 - c * CHUNK;
        dec[c * CPAD + (o >> 2)] = w;
    }
    __syncthreads();

    // ---- B: per-chunk 3-entry-state summary ----
    int c = tid;
    uint32_t dw[CHUNK / 4];
    if (c < NC) {
#pragma unroll
        for (int wi = 0; wi < CHUNK / 4; wi++) dw[wi] = dec[c * CPAD + wi];
        int s0 = 0, s1 = 1, s2 = 2, c0 = 0, c1 = 0, c2 = 0;
#pragma unroll
        for (int t = 0; t < CHUNK; t++) {
            int f0, f1;
            DECODE(dw, t, f0, f1);
            s0 = (s0 == 0) ? f0 : f1;
            s1 = (s1 == 0) ? f0 : f1;
            s2 = (s2 == 0) ? f0 : f1;
            bool skip = (c == 0) && (t == 0);   // tumble[t=0] forced False
            c0 += (s0 == 2 && !skip);
            c1 += (s1 == 2 && !skip);
            c2 += (s2 == 2 && !skip);
        }
        S[c] = make_uint4((unsigned)(s0 | (s1 << 2) | (s2 << 4)),
                          (unsigned)c0, (unsigned)c1, (unsigned)c2);
    }
    __syncthreads();

    // ---- C: Hillis-Steele inclusive scan of S (8 rounds) ----
    for (int off = 1; off < NC; off <<= 1) {
        uint4 prev;
        bool act = (c < NC) && (c >= off);
        if (act) prev = S[c - off];
        __syncthreads();
        if (act) S[c] = comb2(prev, S[c]);
        __syncthreads();
    }

    // exclusive entry for chunk c (global start s=0, C=0)
    int es = 0;
    uint32_t eC = 0;
    if (c > 0 && c < NC) {
        uint4 E = S[c - 1];
        es = (int)(E.x & 3u);
        eC = E.y;
    }

    float xx0 = x0[b * 3], xy0 = x0[b * 3 + 1], xz0 = x0[b * 3 + 2];

    // ---- D: walk0 -> chunk velocity sums ----
    if (c < NC) {
        int s = es;
        uint32_t C = eC;
        float px = 0.f, py = 0.f, pz = 0.f;
#pragma unroll
        for (int t = 0; t < CHUNK; t++) {
            int f0, f1;
            DECODE(dw, t, f0, f1);
            s = (s == 0) ? f0 : f1;
            float vx, vy, vz;
            if (c == 0 && t == 0) {
                vx = xx0; vy = xy0; vz = xz0;     // vel[:,0,:] = x0, no count
            } else if (s == 2) {
                C++;
                vx = 0.f; vy = 0.f; vz = 0.f;
            } else {
                int idx = (int)C - 1;
                idx = idx < 0 ? 0 : (idx > CAP ? CAP : idx);
                float spd = (s == 1) ? 5e-3f : 1e-3f;
                vx = se[idx * 3] * spd; vy = se[idx * 3 + 1] * spd; vz = se[idx * 3 + 2] * spd;
            }
            px += vx; py += vy; pz += vz;
        }
        Px[c] = px; Py[c] = py; Pz[c] = pz;
    }
    __syncthreads();

    // ---- E: float3 inclusive scan (8 rounds) ----
    for (int off = 1; off < NC; off <<= 1) {
        float ax, ay, az;
        bool act = (c < NC) && (c >= off);
        if (act) { ax = Px[c - off]; ay = Py[c - off]; az = Pz[c - off]; }
        __syncthreads();
        if (act) { Px[c] += ax; Py[c] += ay; Pz[c] += az; }
        __syncthreads();
    }

    // ---- F: walk1, write positions (4 steps -> 3 float4 stores) ----
    if (c < NC) {
        float px = 0.f, py = 0.f, pz = 0.f;
        if (c > 0) { px = Px[c - 1]; py = Py[c - 1]; pz = Pz[c - 1]; }
        int s = es;
        uint32_t C = eC;
        float* op = out + ((size_t)b * NT + (size_t)c * CHUNK) * 3;
#pragma unroll
        for (int g = 0; g < CHUNK / 4; g++) {
            float buf[12];
#pragma unroll
            for (int j = 0; j < 4; j++) {
                int t = g * 4 + j;
                int f0, f1;
                DECODE(dw, t, f0, f1);
                s = (s == 0) ? f0 : f1;
                float vx, vy, vz;
                if (c == 0 && t == 0) {
                    vx = xx0; vy = xy0; vz = xz0;
                } else if (s == 2) {
                    C++;
                    vx = 0.f; vy = 0.f; vz = 0.f;
                } else {
                    int idx = (int)C - 1;
                    idx = idx < 0 ? 0 : (idx > CAP ? CAP : idx);
                    float spd = (s == 1) ? 5e-3f : 1e-3f;
                    vx = se[idx * 3] * spd; vy = se[idx * 3 + 1] * spd; vz = se[idx * 3 + 2] * spd;
                }
                px += vx; py += vy; pz += vz;
                buf[j * 3] = px; buf[j * 3 + 1] = py; buf[j * 3 + 2] = pz;
            }
            float4* o4 = (float4*)(op + g * 12);
            o4[0] = make_float4(buf[0], buf[1], buf[2], buf[3]);
            o4[1] = make_float4(buf[4], buf[5], buf[6], buf[7]);
            o4[2] = make_float4(buf[8], buf[9], buf[10], buf[11]);
        }
    }
}

extern "C" void kernel_launch(void* const* d_in, const int* in_sizes, int n_in,
                              void* d_out, int out_size, void* d_ws, size_t ws_size,
                              hipStream_t stream) {
    const float* x0 = (const float*)d_in[0];
    const float* v0 = (const float*)d_in[1];
    const float* v1 = (const float*)d_in[2];
    const float* r0 = (const float*)d_in[3];
    const float* r1 = (const float*)d_in[4];
    const float* up = (const float*)d_in[5];
    const float* un = (const float*)d_in[6];
    float* out = (float*)d_out;

    char* w = (char*)d_ws;
    float* trig = (float*)w;  w += (size_t)NB * CAP * 4 * sizeof(float);        // 512 kB
    float* e0s = (float*)w;   w += (size_t)NB * (CAP + 1) * 3 * sizeof(float);  // 400 kB

    k_angles<<<dim3(NB * CAP / 256), dim3(256), 0, stream>>>(up, un, trig);
    k_chain<<<dim3(NB / 64), dim3(64), 0, stream>>>(v0, v1, trig, e0s);
    k_row<<<dim3(NB), dim3(256), 0, stream>>>(r0, r1, x0, e0s, out);
}

// Round 7
// 335.202 us; speedup vs baseline: 1.9737x; 1.0520x over previous
//
#include <hip/hip_runtime.h>
#include <math.h>
#include <stdint.h>

#define NB 512
#define NT 20000
#define CAP 64
#define CHUNK 20
#define NC 1000         // NT / CHUNK
#define CW (CHUNK / 4)  // 5 data words per chunk
#define CPAD 6          // 5 data + 1 pad word in LDS
#define NTHR 1024

static_assert(CHUNK * NC == NT, "chunking must cover all steps");
static_assert(CHUNK % 4 == 0, "byte-packing needs 4 | CHUNK");

#define PI_F 3.14159265358979323846f

__device__ __forceinline__ float3 f3(float x, float y, float z) { return make_float3(x, y, z); }

__device__ __forceinline__ float3 norm3(float3 v) {
    float n = sqrtf(v.x * v.x + v.y * v.y + v.z * v.z);
    return f3(v.x / n, v.y / n, v.z / n);
}
__device__ __forceinline__ float3 cross3(float3 a, float3 b) {
    return f3(a.y * b.z - a.z * b.y, a.z * b.x - a.x * b.z, a.x * b.y - a.y * b.x);
}
__device__ __forceinline__ float dot3(float3 a, float3 b) { return a.x * b.x + a.y * b.y + a.z * b.z; }
__device__ __forceinline__ float3 orth3(float3 v, float3 u) {
    float d = dot3(v, u) / dot3(u, u);
    return f3(v.x - d * u.x, v.y - d * u.y, v.z - d * u.z);
}
__device__ __forceinline__ float3 rotv(float3 u, float c, float s, float3 v) {
    float3 cv = cross3(u, v);
    float du = dot3(u, v) * (1.0f - c);
    return f3(c * v.x + s * cv.x + du * u.x,
              c * v.y + s * cv.y + du * u.y,
              c * v.z + s * cv.z + du * u.z);
}

__device__ __forceinline__ float cauchy_ang(float u, float sigma) {
    float x = PI_F * (u - 0.5f);          // f32 argument, as in reference
    float t = (float)tan((double)x);      // near-correctly-rounded tan of that f32 arg
    float a = sigma * t;                  // mu = 0
    if (!isfinite(a)) a = 0.0f;
    return fmodf(a, PI_F);
}

// ---- kernel 1: parallel Cauchy angles + trig -> trig[k][b] = {cp,sp,cn,sn} ----
__global__ __launch_bounds__(256) void k_angles(const float* __restrict__ up, const float* __restrict__ un,
                                                float* __restrict__ trig) {
    int tid = blockIdx.x * 256 + threadIdx.x;   // tid = k*NB + b
    int k = tid >> 9, b = tid & (NB - 1);
    float ap = cauchy_ang(up[b * CAP + k], 0.1f);
    float an = cauchy_ang(un[b * CAP + k], 0.5f);
    ((float4*)trig)[tid] = make_float4(cosf(ap), sinf(ap), cosf(an), sinf(an));
}

// ---- kernel 2: sequential frame chain (pure f32 arith) -> e0s[b][65][3] ----
__global__ __launch_bounds__(64) void k_chain(const float* __restrict__ v0, const float* __restrict__ v1,
                                              const float* __restrict__ trig, float* __restrict__ e0s) {
    int b = blockIdx.x * 64 + threadIdx.x;
    if (b >= NB) return;
    float3 a0 = f3(v0[b * 3], v0[b * 3 + 1], v0[b * 3 + 2]);
    float3 a1 = f3(v1[b * 3], v1[b * 3 + 1], v1[b * 3 + 2]);
    float3 e0 = norm3(a0);
    float3 e1 = norm3(orth3(a1, e0));
    float3 e2 = norm3(cross3(e0, e1));
    float* o = e0s + (size_t)b * (CAP + 1) * 3;
    o[0] = e0.x; o[1] = e0.y; o[2] = e0.z;
    for (int k = 0; k < CAP; k++) {
        float4 t4 = ((const float4*)trig)[k * NB + b];
        float cp = t4.x, sp = t4.y, cn = t4.z, sn = t4.w;
        float3 e0r = rotv(e2, cp, sp, e0);
        float3 e1r = rotv(e2, cp, sp, e1);
        e0 = norm3(e0r);
        e1 = norm3(e1r);
        e1 = norm3(orth3(e1, e0));
        e2 = norm3(cross3(e0, e1));
        e0 = norm3(rotv(e1, cn, sn, e0));
        e1 = norm3(orth3(e1, e0));
        e2 = norm3(cross3(e0, e1));
        o[(k + 1) * 3] = e0.x; o[(k + 1) * 3 + 1] = e0.y; o[(k + 1) * 3 + 2] = e0.z;
    }
}

// combine two scan elements: apply A then B.  elem = {map(3x2b), c0, c1, c2}
__device__ __forceinline__ uint4 comb2(uint4 A, uint4 B) {
    uint4 R;
    R.x = 0;
    {
        unsigned ms = A.x & 3u;
        unsigned mf = (B.x >> (2u * ms)) & 3u;
        R.x |= mf;
        unsigned cB = (ms == 0u) ? B.y : ((ms == 1u) ? B.z : B.w);
        R.y = A.y + cB;
    }
    {
        unsigned ms = (A.x >> 2) & 3u;
        unsigned mf = (B.x >> (2u * ms)) & 3u;
        R.x |= mf << 2;
        unsigned cB = (ms == 0u) ? B.y : ((ms == 1u) ? B.z : B.w);
        R.z = A.z + cB;
    }
    {
        unsigned ms = (A.x >> 4) & 3u;
        unsigned mf = (B.x >> (2u * ms)) & 3u;
        R.x |= mf << 4;
        unsigned cB = (ms == 0u) ? B.y : ((ms == 1u) ? B.z : B.w);
        R.w = A.w + cB;
    }
    return R;
}

#define DECODE(dw, t, f0, f1)                                        \
    {                                                                \
        uint32_t by_ = (dw[(t) >> 2] >> (((t) & 3) * 8)) & 0xFFu;    \
        f0 = (int)(by_ & 3u);                                        \
        f1 = (int)((by_ >> 2) & 1u);                                 \
    }

// ---- kernel 3: the whole per-b pipeline in one 1024-thread block ----
__global__ __launch_bounds__(NTHR, 4) void k_row(const float* __restrict__ r0, const float* __restrict__ r1,
                                                 const float* __restrict__ x0, const float* __restrict__ e0s,
                                                 float* __restrict__ out) {
    __shared__ uint32_t dec[NC * CPAD];      // decision bytes, padded per chunk (24 kB)
    __shared__ float se[(CAP + 1) * 3];      // frame table
    __shared__ uint4 S[NC];                  // (map,counts) scan (16 kB)
    __shared__ float Px[NC], Py[NC], Pz[NC]; // position scan (12 kB)

    int b = blockIdx.x, tid = threadIdx.x;

    // ---- A: load frames + pack decision bytes into LDS ----
    if (tid < (CAP + 1) * 3)
        se[tid] = e0s[(size_t)b * (CAP + 1) * 3 + tid];

    const float4* q0 = (const float4*)(r0 + (size_t)b * NT);
    const float4* q1 = (const float4*)(r1 + (size_t)b * NT);
    for (int T = tid; T < NT / 4; T += NTHR) {
        float4 a = q0[T], d = q1[T];
        float ra[4] = {a.x, a.y, a.z, a.w};
        float rd[4] = {d.x, d.y, d.z, d.w};
        uint32_t w = 0;
#pragma unroll
        for (int j = 0; j < 4; j++) {
            int f0 = (ra[j] < 1e-3f) ? 1 : ((ra[j] > (1.0f - 1e-3f)) ? 2 : 0);
            int f1 = (rd[j] < 1e-3f) ? 0 : 1;
            w |= (uint32_t)(f0 | (f1 << 2)) << (8 * j);
        }
        int c = T / CW;                 // CHUNK=20 -> 5 words per chunk
        int o = T - c * CW;
        dec[c * CPAD + o] = w;
    }
    __syncthreads();

    // ---- B: per-chunk 3-entry-state summary ----
    int c = tid;
    uint32_t dw[CW];
    if (c < NC) {
#pragma unroll
        for (int wi = 0; wi < CW; wi++) dw[wi] = dec[c * CPAD + wi];
        int s0 = 0, s1 = 1, s2 = 2, c0 = 0, c1 = 0, c2 = 0;
#pragma unroll
        for (int t = 0; t < CHUNK; t++) {
            int f0, f1;
            DECODE(dw, t, f0, f1);
            s0 = (s0 == 0) ? f0 : f1;
            s1 = (s1 == 0) ? f0 : f1;
            s2 = (s2 == 0) ? f0 : f1;
            bool skip = (c == 0) && (t == 0);   // tumble[t=0] forced False
            c0 += (s0 == 2 && !skip);
            c1 += (s1 == 2 && !skip);
            c2 += (s2 == 2 && !skip);
        }
        S[c] = make_uint4((unsigned)(s0 | (s1 << 2) | (s2 << 4)),
                          (unsigned)c0, (unsigned)c1, (unsigned)c2);
    }
    __syncthreads();

    // ---- C: Hillis-Steele inclusive scan of S (10 rounds) ----
    for (int off = 1; off < NC; off <<= 1) {
        uint4 prev;
        bool act = (c < NC) && (c >= off);
        if (act) prev = S[c - off];
        __syncthreads();
        if (act) S[c] = comb2(prev, S[c]);
        __syncthreads();
    }

    // exclusive entry for chunk c (global start s=0, C=0)
    int es = 0;
    uint32_t eC = 0;
    if (c > 0 && c < NC) {
        uint4 E = S[c - 1];
        es = (int)(E.x & 3u);
        eC = E.y;
    }

    float xx0 = x0[b * 3], xy0 = x0[b * 3 + 1], xz0 = x0[b * 3 + 2];

    // ---- D: walk0 -> chunk velocity sums ----
    if (c < NC) {
        int s = es;
        uint32_t C = eC;
        float px = 0.f, py = 0.f, pz = 0.f;
#pragma unroll
        for (int t = 0; t < CHUNK; t++) {
            int f0, f1;
            DECODE(dw, t, f0, f1);
            s = (s == 0) ? f0 : f1;
            float vx, vy, vz;
            if (c == 0 && t == 0) {
                vx = xx0; vy = xy0; vz = xz0;     // vel[:,0,:] = x0, no count
            } else if (s == 2) {
                C++;
                vx = 0.f; vy = 0.f; vz = 0.f;
            } else {
                int idx = (int)C - 1;
                idx = idx < 0 ? 0 : (idx > CAP ? CAP : idx);
                float spd = (s == 1) ? 5e-3f : 1e-3f;
                vx = se[idx * 3] * spd; vy = se[idx * 3 + 1] * spd; vz = se[idx * 3 + 2] * spd;
            }
            px += vx; py += vy; pz += vz;
        }
        Px[c] = px; Py[c] = py; Pz[c] = pz;
    }
    __syncthreads();

    // ---- E: float3 inclusive scan (10 rounds) ----
    for (int off = 1; off < NC; off <<= 1) {
        float ax, ay, az;
        bool act = (c < NC) && (c >= off);
        if (act) { ax = Px[c - off]; ay = Py[c - off]; az = Pz[c - off]; }
        __syncthreads();
        if (act) { Px[c] += ax; Py[c] += ay; Pz[c] += az; }
        __syncthreads();
    }

    // ---- F: walk1, write positions (4 steps -> 3 float4 stores) ----
    if (c < NC) {
        float px = 0.f, py = 0.f, pz = 0.f;
        if (c > 0) { px = Px[c - 1]; py = Py[c - 1]; pz = Pz[c - 1]; }
        int s = es;
        uint32_t C = eC;
        float* op = out + ((size_t)b * NT + (size_t)c * CHUNK) * 3;
#pragma unroll
        for (int g = 0; g < CW; g++) {
            float buf[12];
#pragma unroll
            for (int j = 0; j < 4; j++) {
                int t = g * 4 + j;
                int f0, f1;
                DECODE(dw, t, f0, f1);
                s = (s == 0) ? f0 : f1;
                float vx, vy, vz;
                if (c == 0 && t == 0) {
                    vx = xx0; vy = xy0; vz = xz0;
                } else if (s == 2) {
                    C++;
                    vx = 0.f; vy = 0.f; vz = 0.f;
                } else {
                    int idx = (int)C - 1;
                    idx = idx < 0 ? 0 : (idx > CAP ? CAP : idx);
                    float spd = (s == 1) ? 5e-3f : 1e-3f;
                    vx = se[idx * 3] * spd; vy = se[idx * 3 + 1] * spd; vz = se[idx * 3 + 2] * spd;
                }
                px += vx; py += vy; pz += vz;
                buf[j * 3] = px; buf[j * 3 + 1] = py; buf[j * 3 + 2] = pz;
            }
            float4* o4 = (float4*)(op + g * 12);
            o4[0] = make_float4(buf[0], buf[1], buf[2], buf[3]);
            o4[1] = make_float4(buf[4], buf[5], buf[6], buf[7]);
            o4[2] = make_float4(buf[8], buf[9], buf[10], buf[11]);
        }
    }
}

extern "C" void kernel_launch(void* const* d_in, const int* in_sizes, int n_in,
                              void* d_out, int out_size, void* d_ws, size_t ws_size,
                              hipStream_t stream) {
    const float* x0 = (const float*)d_in[0];
    const float* v0 = (const float*)d_in[1];
    const float* v1 = (const float*)d_in[2];
    const float* r0 = (const float*)d_in[3];
    const float* r1 = (const float*)d_in[4];
    const float* up = (const float*)d_in[5];
    const float* un = (const float*)d_in[6];
    float* out = (float*)d_out;

    char* w = (char*)d_ws;
    float* trig = (float*)w;  w += (size_t)NB * CAP * 4 * sizeof(float);        // 512 kB
    float* e0s = (float*)w;   w += (size_t)NB * (CAP + 1) * 3 * sizeof(float);  // 400 kB

    k_angles<<<dim3(NB * CAP / 256), dim3(256), 0, stream>>>(up, un, trig);
    k_chain<<<dim3(NB / 64), dim3(64), 0, stream>>>(v0, v1, trig, e0s);
    k_row<<<dim3(NB), dim3(NTHR), 0, stream>>>(r0, r1, x0, e0s, out);
}